// Round 8
// baseline (391.429 us; speedup 1.0000x reference)
//
#include <hip/hip_runtime.h>
#include <cstdint>
#include <cstddef>

#define HH 12
#define DHD 64
#define BB 64
#define SS 512
#define DD 768
#define PP 256
#define N3 2304

typedef __attribute__((ext_vector_type(8))) short bf16x8_t;
typedef __attribute__((ext_vector_type(4))) float f32x4_t;

__constant__ float c_slopes[12] = {
  0.5f, 0.25f, 0.125f, 0.0625f, 0.03125f, 0.015625f, 0.0078125f, 0.00390625f,
  0.70710678118654752f, 0.35355339059327376f, 0.17677669529663688f, 0.08838834764831844f
};

__device__ __forceinline__ ushort f2bf(float f) {
  union { float f; unsigned u; } v; v.f = f;
  unsigned r = v.u + 0x7fffu + ((v.u >> 16) & 1u);  // RNE
  return (ushort)(r >> 16);
}
__device__ __forceinline__ float bf2f(ushort u) {
  union { unsigned u; float f; } v; v.u = ((unsigned)u) << 16;
  return v.f;
}
__device__ __forceinline__ void gload_lds16(const ushort* g, ushort* l) {
  __builtin_amdgcn_global_load_lds(
      (const __attribute__((address_space(1))) void*)g,
      (__attribute__((address_space(3))) void*)l, 16, 0, 0);
}

// ---------------- prep: cast hs -> A bf16, masked-pool hs -> Ap bf16, new_mask,
//                  and transpose/cast W -> Wt. (unchanged from r7, verified)
__global__ __launch_bounds__(256) void prep_kernel(
    const float* __restrict__ hs, const int* __restrict__ mask,
    ushort* __restrict__ A, ushort* __restrict__ Ap,
    const float* __restrict__ W, ushort* __restrict__ Wt,
    float* __restrict__ nmask_out) {
  if (blockIdx.x < 8192) {
    const int row0 = blockIdx.x * 4;               // global hs row, pair-aligned
    const int t = threadIdx.x;
    if (t < 192) {                                 // 192 float4 per row
      float4 v[4];
#pragma unroll
      for (int r = 0; r < 4; r++) {
        v[r] = ((const float4*)hs)[(size_t)(row0 + r) * 192 + t];
        ushort4 o;
        o.x = f2bf(v[r].x); o.y = f2bf(v[r].y); o.z = f2bf(v[r].z); o.w = f2bf(v[r].w);
        ((ushort4*)A)[(size_t)(row0 + r) * 192 + t] = o;
      }
      const int m0 = mask[row0], m1 = mask[row0 + 1];
      const int m2 = mask[row0 + 2], m3 = mask[row0 + 3];
      const float f0 = (float)m0, f1 = (float)m1, f2 = (float)m2, f3 = (float)m3;
      const float inv0 = 1.0f / (float)((m0 + m1) < 1 ? 1 : (m0 + m1));
      const float inv1 = 1.0f / (float)((m2 + m3) < 1 ? 1 : (m2 + m3));
      ushort4 p0, p1;
      p0.x = f2bf((f0 * v[0].x + f1 * v[1].x) * inv0);
      p0.y = f2bf((f0 * v[0].y + f1 * v[1].y) * inv0);
      p0.z = f2bf((f0 * v[0].z + f1 * v[1].z) * inv0);
      p0.w = f2bf((f0 * v[0].w + f1 * v[1].w) * inv0);
      p1.x = f2bf((f2 * v[2].x + f3 * v[3].x) * inv1);
      p1.y = f2bf((f2 * v[2].y + f3 * v[3].y) * inv1);
      p1.z = f2bf((f2 * v[2].z + f3 * v[3].z) * inv1);
      p1.w = f2bf((f2 * v[2].w + f3 * v[3].w) * inv1);
      const int prow = row0 >> 1;
      ((ushort4*)Ap)[(size_t)prow * 192 + t]       = p0;
      ((ushort4*)Ap)[(size_t)(prow + 1) * 192 + t] = p1;
      if (t == 0) {
        nmask_out[prow]     = (m0 + m1) > 0 ? 1.0f : 0.0f;
        nmask_out[prow + 1] = (m2 + m3) > 0 ? 1.0f : 0.0f;
      }
    }
  } else {
    __shared__ float tile[32][33];
    int tb = blockIdx.x - 8192;                    // 72 * 24 tiles
    int n0 = (tb % 72) * 32, k0 = (tb / 72) * 32;
    int tx = threadIdx.x & 31, ty = threadIdx.x >> 5;
    for (int r = ty; r < 32; r += 8) tile[r][tx] = W[(size_t)(k0 + r) * N3 + n0 + tx];
    __syncthreads();
    for (int r = ty; r < 32; r += 8) Wt[(size_t)(n0 + r) * DD + k0 + tx] = f2bf(tile[tx][r]);
  }
}

// ---------------- GEMM: 256x256, BK=64, faithful 8-phase counted-vmcnt (m201 template) ---
// Per iter i: K-tiles (2i -> buf0, 2i+1 -> buf1), 8 phases. Each phase:
//   {frag ds_reads | ONE half-tile stage (2 gload_lds) | [vmcnt @ph3/ph7]} -> barrier
//   -> lgkmcnt(0)+sched_barrier -> setprio(1) 16 MFMA setprio(0) -> barrier.
// Stage targets (into the buf being read; WAR-safe by phase-close ledger):
//   ph0: B(2i+1) l23 | ph1: A(2i+2) l02 | ph2: B(2i+2) l01 | ph3: A(2i+2) l13 + vmcnt
//   ph4: B(2i+2) l23 | ph5: A(2i+3) l02 | ph6: B(2i+3) l01 | ph7: A(2i+3) l13 + vmcnt
// vmcnt(6) = 3 half-tiles in flight; retires exactly the tile the next phase-group reads.
// Last iter (i=5): no ph1-7 stages; ph3 uses vmcnt(0) (only 2 loads outstanding).
__global__ __launch_bounds__(512, 2) void gemm_qkv_kernel(
    const ushort* __restrict__ A, const ushort* __restrict__ Ap,
    const ushort* __restrict__ Wt, const float* __restrict__ bias,
    const int* __restrict__ mask, const float* __restrict__ nmask,
    ushort* __restrict__ Kbuf, ushort* __restrict__ Vbuf,
    float* __restrict__ resid, ushort* __restrict__ qp) {
  __shared__ __align__(16) ushort As[2][16384];
  __shared__ __align__(16) ushort Bs[2][16384];
  const int wg = blockIdx.x;
  const int swz = (wg & 7) * 120 + (wg >> 3);
  int bm, wtb; const ushort* Asrc; bool isQ;
  if (swz < 768) { isQ = false; bm = (swz / 6) * 256; wtb = 768 + (swz % 6) * 256; Asrc = A; }
  else { isQ = true; int q = swz - 768; bm = (q / 3) * 256; wtb = (q % 3) * 256; Asrc = Ap; }
  const int tid = threadIdx.x;
  const int lane = tid & 63;
  const int wave = tid >> 6;
  const int wm = (wave >> 2) * 128;       // 2 M-halves
  const int wn = (wave & 3) * 64;         // 4 N-quarters
  const int fr = lane & 15, quad = lane >> 4;
  const int xr = (fr & 7) << 3;           // swizzle XOR in ushort units
  const int q8 = quad * 8;

  const int rsub = tid >> 3;
  const int cg8 = ((tid & 7) ^ (rsub & 7)) * 8;
  const ushort* Ag = Asrc + (size_t)(bm + rsub) * DD + cg8;
  const ushort* Bg = Wt + (size_t)(wtb + rsub) * DD + cg8;
  ushort* AsW = &As[0][0] + wave * 512;
  ushort* BsW = &Bs[0][0] + wave * 512;
  const ushort* A0 = &As[0][0]; const ushort* B0 = &Bs[0][0];
  const ushort* A1 = &As[1][0]; const ushort* B1 = &Bs[1][0];

#define ST_A(tt, l0, l1) { const size_t ko = (size_t)(tt) * 64;                      \
    ushort* d = AsW + (((tt) & 1) << 14);                                            \
    gload_lds16(Ag + (size_t)(l0) * 64 * DD + ko, d + (l0) * 4096);                  \
    gload_lds16(Ag + (size_t)(l1) * 64 * DD + ko, d + (l1) * 4096); }
#define ST_B(tt, l0, l1) { const size_t ko = (size_t)(tt) * 64;                      \
    ushort* d = BsW + (((tt) & 1) << 14);                                            \
    gload_lds16(Bg + (size_t)(l0) * 64 * DD + ko, d + (l0) * 4096);                  \
    gload_lds16(Bg + (size_t)(l1) * 64 * DD + ko, d + (l1) * 4096); }
#define RD_A(dst, Ab, mh)                                                            \
  _Pragma("unroll") for (int m = 0; m < 4; m++)                                      \
  _Pragma("unroll") for (int kk = 0; kk < 2; kk++)                                   \
    dst[m][kk] = *(const bf16x8_t*)&Ab[(wm + (mh) * 64 + m * 16 + fr) * 64 + ((kk * 32 + q8) ^ xr)];
#define RD_B(dst, Bb, nh)                                                            \
  _Pragma("unroll") for (int n = 0; n < 2; n++)                                      \
  _Pragma("unroll") for (int kk = 0; kk < 2; kk++)                                   \
    dst[n][kk] = *(const bf16x8_t*)&Bb[(wn + (nh) * 32 + n * 16 + fr) * 64 + ((kk * 32 + q8) ^ xr)];
#define PH_MID                                                                        \
    asm volatile("" ::: "memory");                                                    \
    __builtin_amdgcn_s_barrier();                                                     \
    asm volatile("s_waitcnt lgkmcnt(0)" ::: "memory");                                \
    __builtin_amdgcn_sched_barrier(0);                                                \
    __builtin_amdgcn_s_setprio(1);
#define PH_END                                                                        \
    __builtin_amdgcn_s_setprio(0);                                                    \
    asm volatile("" ::: "memory");                                                    \
    __builtin_amdgcn_s_barrier();
#define MM(mb, nb, aa, bb_)                                                           \
  _Pragma("unroll") for (int m = 0; m < 4; m++)                                       \
  _Pragma("unroll") for (int n = 0; n < 2; n++) {                                     \
    acc[(mb)+m][(nb)+n] = __builtin_amdgcn_mfma_f32_16x16x32_bf16(aa[m][0], bb_[n][0], acc[(mb)+m][(nb)+n], 0, 0, 0); \
    acc[(mb)+m][(nb)+n] = __builtin_amdgcn_mfma_f32_16x16x32_bf16(aa[m][1], bb_[n][1], acc[(mb)+m][(nb)+n], 0, 0, 0); }

  f32x4_t acc[8][4];
#pragma unroll
  for (int i = 0; i < 8; i++)
#pragma unroll
    for (int j = 0; j < 4; j++) acc[i][j] = (f32x4_t){0.f, 0.f, 0.f, 0.f};

  // prologue: tile0 full (8 loads) + tile1 partial A02,B01,A13 (6); vmcnt(6) retires tile0.
  ST_A(0, 0, 1); ST_A(0, 2, 3); ST_B(0, 0, 1); ST_B(0, 2, 3);
  ST_A(1, 0, 2); ST_B(1, 0, 1); ST_A(1, 1, 3);
  asm volatile("s_waitcnt vmcnt(6)" ::: "memory");
  __builtin_amdgcn_s_barrier();
  asm volatile("" ::: "memory");

#pragma unroll 1
  for (int i = 0; i < 6; i++) {
    bf16x8_t a[4][2], b0[2][2], b1[2][2];
    const bool st = (i < 5);
    // ---------- K-tile 2i (buf0) ----------
    // ph0
    RD_A(a, A0, 0); RD_B(b0, B0, 0);
    ST_B(2 * i + 1, 2, 3);
    PH_MID; MM(0, 0, a, b0); PH_END;
    // ph1
    RD_B(b1, B0, 1);
    if (st) ST_A(2 * i + 2, 0, 2);
    PH_MID; MM(0, 2, a, b1); PH_END;
    // ph2
    RD_A(a, A0, 1);
    if (st) ST_B(2 * i + 2, 0, 1);
    PH_MID; MM(4, 0, a, b0); PH_END;
    // ph3  (vmcnt retires tile 2i+1 before buf1 reads)
    if (st) { ST_A(2 * i + 2, 1, 3);
              asm volatile("s_waitcnt vmcnt(6)" ::: "memory"); }
    else    { asm volatile("s_waitcnt vmcnt(0)" ::: "memory"); }
    PH_MID; MM(4, 2, a, b1); PH_END;
    // ---------- K-tile 2i+1 (buf1) ----------
    // ph4
    RD_A(a, A1, 0); RD_B(b0, B1, 0);
    if (st) ST_B(2 * i + 2, 2, 3);
    PH_MID; MM(0, 0, a, b0); PH_END;
    // ph5
    RD_B(b1, B1, 1);
    if (st) ST_A(2 * i + 3, 0, 2);
    PH_MID; MM(0, 2, a, b1); PH_END;
    // ph6
    RD_A(a, A1, 1);
    if (st) ST_B(2 * i + 3, 0, 1);
    PH_MID; MM(4, 0, a, b0); PH_END;
    // ph7  (vmcnt retires tile 2i+2 before next iter's buf0 reads)
    if (st) { ST_A(2 * i + 3, 1, 3);
              asm volatile("s_waitcnt vmcnt(6)" ::: "memory"); }
    else    { asm volatile("s_waitcnt vmcnt(0)" ::: "memory"); }
    PH_MID; MM(4, 2, a, b1); PH_END;
  }

  // ---- epilogue ----
  float bb[4];
#pragma unroll
  for (int j = 0; j < 4; j++) bb[j] = bias[wtb + wn + j * 16 + fr];
  if (!isQ) {
    ushort* dst = (wtb < 1536) ? Kbuf : Vbuf;
    const int cb = (wtb < 1536) ? (wtb - 768) : (wtb - 1536);
#pragma unroll
    for (int i = 0; i < 8; i++) {
      const int gm = bm + wm + i * 16 + quad * 4;
#pragma unroll
      for (int r = 0; r < 4; r++) {
        const float mv = (float)mask[gm + r];
        ushort* orow = dst + (size_t)(gm + r) * DD + cb + wn + fr;
#pragma unroll
        for (int j = 0; j < 4; j++)
          orow[j * 16] = f2bf((acc[i][j][r] + bb[j]) * mv);
      }
    }
  } else {
#pragma unroll
    for (int i = 0; i < 8; i++) {
      const int gm = bm + wm + i * 16 + quad * 4;
#pragma unroll
      for (int r = 0; r < 4; r++) {
        const float qm = nmask[gm + r];
        float* rrow = resid + (size_t)(gm + r) * DD + wtb + wn + fr;
        ushort* qrow = qp + (size_t)(gm + r) * DD + wtb + wn + fr;
#pragma unroll
        for (int j = 0; j < 4; j++) {
          float v = acc[i][j][r] + bb[j] * qm;
          rrow[j * 16] = v;
          qrow[j * 16] = f2bf(v * 0.125f);
        }
      }
    }
  }
#undef ST_A
#undef ST_B
#undef RD_A
#undef RD_B
#undef PH_MID
#undef PH_END
#undef MM
}

// ---------------- attention: one block per (h,b), flash-style, LDS-resident K/V^T --------
// (unchanged from r7, verified)
__global__ __launch_bounds__(512, 2) void attn_kernel(
    const ushort* __restrict__ Kbuf, const ushort* __restrict__ Vbuf,
    const ushort* __restrict__ qp,
    const int* __restrict__ mask, const float* __restrict__ nmask,
    float* __restrict__ outA) {
  __shared__ __align__(16) ushort K_lds[512 * 64];
  __shared__ __align__(16) ushort VT_lds[64 * 512];
  __shared__ __align__(16) ushort P_lds[8][32][40];
  __shared__ __align__(16) float  kb[512];
  const int h = blockIdx.x, b = blockIdx.y;
  const int tid = threadIdx.x, wave = tid >> 6, lane = tid & 63;
  const int fr = lane & 15, quad = lane >> 4;
  const int kxor = (fr & 7) << 4;                 // byte-XOR for swizzled LDS reads
  const float slope = c_slopes[h];

  {
    const int r0 = lane >> 3;
    const int cg = ((lane & 7) ^ r0) * 8;         // inverse-swizzled source chunk
    const ushort* Ks = Kbuf + (size_t)(b * 512 + wave * 64 + r0) * DD + h * 64 + cg;
#pragma unroll
    for (int i = 0; i < 8; i++)
      gload_lds16(Ks + (size_t)i * 8 * DD, K_lds + (wave * 64 + i * 8) * 64);
  }
  {
    const ushort* Vs = Vbuf + (size_t)(b * 512 + tid) * DD + h * 64;
    float4 vr[8];
#pragma unroll
    for (int d0 = 0; d0 < 8; d0++) vr[d0] = *(const float4*)(Vs + d0 * 8);
    const int s2 = tid * 2;                       // byte col in VT row
    const int sbase = (s2 & ~15), slo = (s2 & 15);
#pragma unroll
    for (int d0 = 0; d0 < 8; d0++) {
      ushort tmp[8];
      *(float4*)tmp = vr[d0];
#pragma unroll
      for (int j = 0; j < 8; j++) {
        int d = d0 * 8 + j;
        *(ushort*)((char*)VT_lds + (size_t)d * 1024 + ((sbase ^ ((d & 7) << 4)) + slo)) = tmp[j];
      }
    }
  }
  kb[tid] = mask[b * 512 + tid] ? 0.0f : -10000.0f;
  bf16x8_t qf[2][2];
#pragma unroll
  for (int nt = 0; nt < 2; nt++)
#pragma unroll
    for (int ks = 0; ks < 2; ks++)
      qf[nt][ks] = *(const bf16x8_t*)(qp + (size_t)(b * 256 + wave * 32 + nt * 16 + fr) * 768
                                      + h * 64 + ks * 32 + quad * 8);
  __syncthreads();

  const char* Kc = (const char*)K_lds;
  const char* Vc = (const char*)VT_lds;
  char* Pw = (char*)&P_lds[wave][0][0];

  f32x4_t O[2][4];
#pragma unroll
  for (int i = 0; i < 2; i++)
#pragma unroll
    for (int j = 0; j < 4; j++) O[i][j] = (f32x4_t){0.f, 0.f, 0.f, 0.f};
  float m_run[2] = {-3.0e38f, -3.0e38f};
  float l_run[2] = {0.f, 0.f};

  for (int sb = 0; sb < 512; sb += 64) {
    f32x4_t sacc[4][2];
#pragma unroll
    for (int mt = 0; mt < 4; mt++) { sacc[mt][0] = (f32x4_t){0,0,0,0}; sacc[mt][1] = (f32x4_t){0,0,0,0}; }
#pragma unroll
    for (int ks = 0; ks < 2; ks++)
#pragma unroll
      for (int mt = 0; mt < 4; mt++) {
        bf16x8_t ak = *(const bf16x8_t*)(Kc + (size_t)(sb + mt * 16 + fr) * 128
                                         + ((ks * 64 + quad * 16) ^ kxor));
        sacc[mt][0] = __builtin_amdgcn_mfma_f32_16x16x32_bf16(ak, qf[0][ks], sacc[mt][0], 0, 0, 0);
        sacc[mt][1] = __builtin_amdgcn_mfma_f32_16x16x32_bf16(ak, qf[1][ks], sacc[mt][1], 0, 0, 0);
      }
    float kbv[4][4];
#pragma unroll
    for (int mt = 0; mt < 4; mt++) {
      f32x4_t kv = *(const f32x4_t*)&kb[sb + mt * 16 + quad * 4];
#pragma unroll
      for (int r = 0; r < 4; r++) kbv[mt][r] = kv[r];
    }
    float pv2[2][4][4];
    float fsv[2];
#pragma unroll
    for (int nt = 0; nt < 2; nt++) {
      const float pidx = (float)(wave * 32 + nt * 16 + fr);
      float mx = -3.0e38f;
#pragma unroll
      for (int mt = 0; mt < 4; mt++)
#pragma unroll
        for (int r = 0; r < 4; r++) {
          float s_ = (float)(sb + mt * 16 + quad * 4 + r);
          float v = sacc[mt][nt][r] + kbv[mt][r] - slope * fabsf(s_ - pidx);
          pv2[nt][mt][r] = v;
          mx = fmaxf(mx, v);
        }
      mx = fmaxf(mx, __shfl_xor(mx, 16, 64));
      mx = fmaxf(mx, __shfl_xor(mx, 32, 64));
      float mnew = fmaxf(m_run[nt], mx);
      float f = __expf(m_run[nt] - mnew);
      m_run[nt] = mnew; fsv[nt] = f;
      float rs = 0.f;
#pragma unroll
      for (int mt = 0; mt < 4; mt++)
#pragma unroll
        for (int r = 0; r < 4; r++) {
          float e = __expf(pv2[nt][mt][r] - mnew);
          pv2[nt][mt][r] = e; rs += e;
        }
      rs += __shfl_xor(rs, 16, 64);
      rs += __shfl_xor(rs, 32, 64);
      l_run[nt] = l_run[nt] * f + rs;
    }
#pragma unroll
    for (int mp = 0; mp < 2; mp++)
#pragma unroll
      for (int r = 0; r < 4; r++) {
        float fb = __shfl(fsv[mp], quad * 4 + r, 64);
#pragma unroll
        for (int nd = 0; nd < 4; nd++) O[mp][nd][r] *= fb;
      }
#pragma unroll
    for (int c = 0; c < 2; c++) {
#pragma unroll
      for (int nt = 0; nt < 2; nt++)
#pragma unroll
        for (int mm = 0; mm < 2; mm++) {
          int mt = c * 2 + mm;
          ushort4 pk;
          pk.x = f2bf(pv2[nt][mt][0]); pk.y = f2bf(pv2[nt][mt][1]);
          pk.z = f2bf(pv2[nt][mt][2]); pk.w = f2bf(pv2[nt][mt][3]);
          *(ushort4*)(Pw + (nt * 16 + fr) * 80 + mm * 32 + quad * 8) = pk;
        }
      bf16x8_t ap0 = *(const bf16x8_t*)(Pw + fr * 80 + quad * 16);
      bf16x8_t ap1 = *(const bf16x8_t*)(Pw + (16 + fr) * 80 + quad * 16);
#pragma unroll
      for (int nd = 0; nd < 4; nd++) {
        bf16x8_t bv = *(const bf16x8_t*)(Vc + (size_t)(nd * 16 + fr) * 1024
                                         + (((sb + c * 32) * 2 + quad * 16) ^ kxor));
        O[0][nd] = __builtin_amdgcn_mfma_f32_16x16x32_bf16(ap0, bv, O[0][nd], 0, 0, 0);
        O[1][nd] = __builtin_amdgcn_mfma_f32_16x16x32_bf16(ap1, bv, O[1][nd], 0, 0, 0);
      }
    }
  }

#pragma unroll
  for (int mp = 0; mp < 2; mp++) {
    const int p0 = wave * 32 + mp * 16 + quad * 4;
#pragma unroll
    for (int r = 0; r < 4; r++) {
      float lb = __shfl(l_run[mp], quad * 4 + r, 64);
      float nm = nmask[b * 256 + p0 + r];
      float scl = nm / lb;
#pragma unroll
      for (int nd = 0; nd < 4; nd++)
        outA[(size_t)(b * 256 + p0 + r) * 768 + h * 64 + nd * 16 + fr] = O[mp][nd][r] * scl;
    }
  }
}

extern "C" void kernel_launch(void* const* d_in, const int* in_sizes, int n_in,
                              void* d_out, int out_size, void* d_ws, size_t ws_size,
                              hipStream_t stream) {
  const float* hs   = (const float*)d_in[0];
  const int*   mask = (const int*)d_in[1];
  const float* W    = (const float*)d_in[2];
  const float* bias = (const float*)d_in[3];
  float* out = (float*)d_out;
  char* ws = (char*)d_ws;
  // ws layout (bytes):
  //   A    [0,         50331648)   32768x768 bf16
  //   Wt   [50331648,  53870592)   2304x768 bf16
  //   Kbuf [53870592,  104202240)  32768x768 bf16
  //   Vbuf [104202240, 154533888)  32768x768 bf16
  //   Ap   [154533888, 179699712)  16384x768 bf16 (pooled hidden)
  //   qp   [179699712, 204865536)  16384x768 bf16 (pooled q * 1/8)
  ushort* A    = (ushort*)(ws);
  ushort* Wt   = (ushort*)(ws + 50331648);
  ushort* Kbuf = (ushort*)(ws + 53870592);
  ushort* Vbuf = (ushort*)(ws + 104202240);
  ushort* Ap   = (ushort*)(ws + 154533888);
  ushort* qp   = (ushort*)(ws + 179699712);
  float* nmask = out + 12582912;
  float* resid = out + 12599296;

  hipLaunchKernelGGL(prep_kernel, dim3(9920), dim3(256), 0, stream,
                     hs, mask, A, Ap, W, Wt, nmask);
  hipLaunchKernelGGL(gemm_qkv_kernel, dim3(960), dim3(512), 0, stream,
                     A, Ap, Wt, bias, mask, nmask, Kbuf, Vbuf, resid, qp);
  hipLaunchKernelGGL(attn_kernel, dim3(12, 64), dim3(512), 0, stream,
                     Kbuf, Vbuf, qp, mask, nmask, out);
}